// Round 6
// baseline (77.177 us; speedup 1.0000x reference)
//
#include <hip/hip_runtime.h>

// FISM scoring kernel for MI355X (gfx950). R6 = R4 (74.7us) + nontemporal
// hints on the two table row-gather streams (R5 fixed: builtin needs a native
// ext_vector_type pointer, not HIP_vector_type<float,4>).
//
// B=4096 batch rows, N_DOCS=200 candidates, HIST=200 history, F=64 factors.
// One block (256 threads = 4 waves) per batch row; each 16-lane sub-group
// handles one gathered 256B row via float4 loads (1KiB per wave mem inst).
//
// Ladder: R1 82.4 -> R2 76.3 (LDS indices, occ 8/EU, coalesced out)
//         R3 81.0 (two-kernel split REGRESSED - reverted)
//         R4 74.7 (bias-load hoist)
// R6 theory: gathered rows have ~1.46x reuse with temporally-distant random
// repeats -> ~0% L2 hit chance; allocating them in L2 evicts the genuinely
// reusable bias table (4MB, L2-fits) and index lines. nt loads mark the row
// streams evict-first in L2, preserving bias/index residency.

#define FISM_B       4096
#define FISM_NDOCS   200
#define FISM_HIST    200
#define FISM_NF      64

typedef float f32x4 __attribute__((ext_vector_type(4)));

__global__ __launch_bounds__(256, 8) void FISM_55284819034149_kernel(
    const int*   __restrict__ item_lst,        // [B, N_DOCS]
    const int*   __restrict__ past_item_lst,   // [B, HIST]
    const int*   __restrict__ len_past_items,  // [B]
    const float* __restrict__ item_table,      // [N_ITEMS, 64]
    const float* __restrict__ past_item_table, // [N_ITEMS, 64]
    const float* __restrict__ item_bias_table, // [N_ITEMS, 1]
    float*       __restrict__ out)             // [B, N_DOCS]
{
    const int b    = blockIdx.x;
    const int t    = threadIdx.x;
    const int wave = t >> 6;        // 0..3
    const int lane = t & 63;
    const int fgrp = lane & 15;     // factor group: owns factors 4*fgrp .. 4*fgrp+3
    const int sub  = lane >> 4;     // 0..3: row sub-group within the wave
    const int row  = wave * 4 + sub;// 0..15: which gathered row this group owns per trip

    __shared__ int   sPast[FISM_HIST];
    __shared__ int   sDocs[FISM_NDOCS];
    __shared__ float red[4 * 64];   // per-wave pooled partials
    __shared__ float prof[FISM_NF]; // final profile vector
    __shared__ float sc[FISM_NDOCS];// staged scores for coalesced writeback

    // ---------- Stage index lists into LDS (coalesced, removes dependent chain) ----------
    if (t < FISM_HIST)  sPast[t] = past_item_lst[(size_t)b * FISM_HIST + t];
    if (t < FISM_NDOCS) sDocs[t] = item_lst[(size_t)b * FISM_NDOCS + t];
    __syncthreads();

    // ---------- Phase 1: pooled = sum_h mask(past_id>0) * past_item_table[past_id] ----------
    f32x4 acc = (f32x4)0.f;

    #pragma unroll 4
    for (int i = 0; i < 13; ++i) {          // ceil(200/16) trips, 16 rows/block/trip
        int h = i * 16 + row;
        if (h < FISM_HIST) {
            int idx = sPast[h];
            if (idx > 0) {
                const f32x4* p = (const f32x4*)(past_item_table + (size_t)idx * FISM_NF + fgrp * 4);
                const f32x4 v = __builtin_nontemporal_load(p);   // evict-first: no L2 reuse for this stream
                acc += v;
            }
        }
    }

    // Reduce across the 4 sub-groups of this wave (lanes differing in bits 4,5).
    acc.x += __shfl_xor(acc.x, 16); acc.y += __shfl_xor(acc.y, 16);
    acc.z += __shfl_xor(acc.z, 16); acc.w += __shfl_xor(acc.w, 16);
    acc.x += __shfl_xor(acc.x, 32); acc.y += __shfl_xor(acc.y, 32);
    acc.z += __shfl_xor(acc.z, 32); acc.w += __shfl_xor(acc.w, 32);

    if (sub == 0) {
        // lanes 0..15 of each wave hold the wave's pooled sum for factors 4*fgrp..+3
        ((f32x4*)red)[wave * 16 + fgrp] = acc;
    }
    __syncthreads();

    if (t < FISM_NF) {
        float pooled = red[t] + red[64 + t] + red[128 + t] + red[192 + t];
        float len    = (float)len_past_items[b];
        float coeff  = 1.0f / sqrtf(len);   // len^{-0.5}; sqrtf for tight tolerance
        prof[t] = coeff * pooled;
    }
    __syncthreads();

    // ---------- Phase 2: scores[b,d] = dot(profile, mask*item_table[id]) + bias[id] ----------
    const f32x4 pv = *(const f32x4*)(prof + fgrp * 4);

    #pragma unroll 4
    for (int i = 0; i < 13; ++i) {
        int d = i * 16 + row;
        // d is uniform within each 16-lane shuffle group -> divergence-safe.
        if (d < FISM_NDOCS) {
            int idx = sDocs[d];
            // Issue the bias load FIRST so it overlaps the row gather + reduce.
            // (Bias is added unconditionally in the reference, even for id==0.)
            // Bias table is 4MB -> L2-resident; keep it a normal (caching) load.
            float bias = 0.f;
            if (fgrp == 0) bias = item_bias_table[idx];
            float partial = 0.f;
            if (idx > 0) {
                const f32x4* p = (const f32x4*)(item_table + (size_t)idx * FISM_NF + fgrp * 4);
                const f32x4 v = __builtin_nontemporal_load(p);
                partial = v.x * pv.x + v.y * pv.y + v.z * pv.z + v.w * pv.w;
            }
            // Reduce across the 16 lanes of this group.
            partial += __shfl_xor(partial, 1);
            partial += __shfl_xor(partial, 2);
            partial += __shfl_xor(partial, 4);
            partial += __shfl_xor(partial, 8);
            if (fgrp == 0) {
                sc[d] = partial + bias;
            }
        }
    }
    __syncthreads();

    // ---------- Coalesced writeback: 200 floats = 50 float4 ----------
    if (t < FISM_NDOCS / 4) {
        ((f32x4*)(out + (size_t)b * FISM_NDOCS))[t] = ((const f32x4*)sc)[t];
    }
}

extern "C" void kernel_launch(void* const* d_in, const int* in_sizes, int n_in,
                              void* d_out, int out_size, void* d_ws, size_t ws_size,
                              hipStream_t stream) {
    const int*   item_lst        = (const int*)d_in[0];
    const int*   past_item_lst   = (const int*)d_in[1];
    const int*   len_past_items  = (const int*)d_in[2];
    const float* item_table      = (const float*)d_in[3];
    const float* past_item_table = (const float*)d_in[4];
    const float* item_bias_table = (const float*)d_in[5];
    float*       out             = (float*)d_out;

    FISM_55284819034149_kernel<<<FISM_B, 256, 0, stream>>>(
        item_lst, past_item_lst, len_past_items,
        item_table, past_item_table, item_bias_table, out);
}

// Round 7
// 74.969 us; speedup vs baseline: 1.0295x; 1.0295x over previous
//
#include <hip/hip_runtime.h>

// FISM scoring kernel for MI355X (gfx950). R7 = exact revert to R4 (74.7us,
// best known).
//
// B=4096 batch rows, N_DOCS=200 candidates, HIST=200 history, F=64 factors.
// One block (256 threads = 4 waves) per batch row; each 16-lane sub-group
// handles one gathered 256B row via float4 loads (1KiB per wave mem inst).
//
// Ladder: R1 82.4 -> R2 76.3 (LDS indices, occ 8/EU, coalesced out)
//         R3 81.0 (two-kernel split REGRESSED - reverted)
//         R4 74.7 (bias-load hoist)  <- BEST
//         R6 77.2 (nontemporal row loads REGRESSED - reverted; the ~1.46x
//                  row reuse does earn L2/L3 hits, evict-first forfeits them)
//
// Remaining gap vs the 68us all-HBM streaming floor (~9%) is random-256B-
// gather DRAM efficiency - structural for this workload.

#define FISM_B       4096
#define FISM_NDOCS   200
#define FISM_HIST    200
#define FISM_NF      64

__global__ __launch_bounds__(256, 8) void FISM_55284819034149_kernel(
    const int*   __restrict__ item_lst,        // [B, N_DOCS]
    const int*   __restrict__ past_item_lst,   // [B, HIST]
    const int*   __restrict__ len_past_items,  // [B]
    const float* __restrict__ item_table,      // [N_ITEMS, 64]
    const float* __restrict__ past_item_table, // [N_ITEMS, 64]
    const float* __restrict__ item_bias_table, // [N_ITEMS, 1]
    float*       __restrict__ out)             // [B, N_DOCS]
{
    const int b    = blockIdx.x;
    const int t    = threadIdx.x;
    const int wave = t >> 6;        // 0..3
    const int lane = t & 63;
    const int fgrp = lane & 15;     // factor group: owns factors 4*fgrp .. 4*fgrp+3
    const int sub  = lane >> 4;     // 0..3: row sub-group within the wave
    const int row  = wave * 4 + sub;// 0..15: which gathered row this group owns per trip

    __shared__ int   sPast[FISM_HIST];
    __shared__ int   sDocs[FISM_NDOCS];
    __shared__ float red[4 * 64];   // per-wave pooled partials
    __shared__ float prof[FISM_NF]; // final profile vector
    __shared__ float sc[FISM_NDOCS];// staged scores for coalesced writeback

    // ---------- Stage index lists into LDS (coalesced, removes dependent chain) ----------
    if (t < FISM_HIST)  sPast[t] = past_item_lst[(size_t)b * FISM_HIST + t];
    if (t < FISM_NDOCS) sDocs[t] = item_lst[(size_t)b * FISM_NDOCS + t];
    __syncthreads();

    // ---------- Phase 1: pooled = sum_h mask(past_id>0) * past_item_table[past_id] ----------
    float4 acc = make_float4(0.f, 0.f, 0.f, 0.f);

    #pragma unroll 4
    for (int i = 0; i < 13; ++i) {          // ceil(200/16) trips, 16 rows/block/trip
        int h = i * 16 + row;
        if (h < FISM_HIST) {
            int idx = sPast[h];
            if (idx > 0) {
                const float4 v = *(const float4*)(past_item_table + (size_t)idx * FISM_NF + fgrp * 4);
                acc.x += v.x; acc.y += v.y; acc.z += v.z; acc.w += v.w;
            }
        }
    }

    // Reduce across the 4 sub-groups of this wave (lanes differing in bits 4,5).
    acc.x += __shfl_xor(acc.x, 16); acc.y += __shfl_xor(acc.y, 16);
    acc.z += __shfl_xor(acc.z, 16); acc.w += __shfl_xor(acc.w, 16);
    acc.x += __shfl_xor(acc.x, 32); acc.y += __shfl_xor(acc.y, 32);
    acc.z += __shfl_xor(acc.z, 32); acc.w += __shfl_xor(acc.w, 32);

    if (sub == 0) {
        // lanes 0..15 of each wave hold the wave's pooled sum for factors 4*fgrp..+3
        ((float4*)red)[wave * 16 + fgrp] = acc;
    }
    __syncthreads();

    if (t < FISM_NF) {
        float pooled = red[t] + red[64 + t] + red[128 + t] + red[192 + t];
        float len    = (float)len_past_items[b];
        float coeff  = 1.0f / sqrtf(len);   // len^{-0.5}; sqrtf for tight tolerance
        prof[t] = coeff * pooled;
    }
    __syncthreads();

    // ---------- Phase 2: scores[b,d] = dot(profile, mask*item_table[id]) + bias[id] ----------
    const float4 pv = *(const float4*)(prof + fgrp * 4);

    #pragma unroll 4
    for (int i = 0; i < 13; ++i) {
        int d = i * 16 + row;
        // d is uniform within each 16-lane shuffle group -> divergence-safe.
        if (d < FISM_NDOCS) {
            int idx = sDocs[d];
            // Issue the bias load FIRST so it overlaps the row gather + reduce.
            // (Bias is added unconditionally in the reference, even for id==0.)
            float bias = 0.f;
            if (fgrp == 0) bias = item_bias_table[idx];
            float partial = 0.f;
            if (idx > 0) {
                const float4 v = *(const float4*)(item_table + (size_t)idx * FISM_NF + fgrp * 4);
                partial = v.x * pv.x + v.y * pv.y + v.z * pv.z + v.w * pv.w;
            }
            // Reduce across the 16 lanes of this group.
            partial += __shfl_xor(partial, 1);
            partial += __shfl_xor(partial, 2);
            partial += __shfl_xor(partial, 4);
            partial += __shfl_xor(partial, 8);
            if (fgrp == 0) {
                sc[d] = partial + bias;
            }
        }
    }
    __syncthreads();

    // ---------- Coalesced writeback: 200 floats = 50 float4 ----------
    if (t < FISM_NDOCS / 4) {
        ((float4*)(out + (size_t)b * FISM_NDOCS))[t] = ((const float4*)sc)[t];
    }
}

extern "C" void kernel_launch(void* const* d_in, const int* in_sizes, int n_in,
                              void* d_out, int out_size, void* d_ws, size_t ws_size,
                              hipStream_t stream) {
    const int*   item_lst        = (const int*)d_in[0];
    const int*   past_item_lst   = (const int*)d_in[1];
    const int*   len_past_items  = (const int*)d_in[2];
    const float* item_table      = (const float*)d_in[3];
    const float* past_item_table = (const float*)d_in[4];
    const float* item_bias_table = (const float*)d_in[5];
    float*       out             = (float*)d_out;

    FISM_55284819034149_kernel<<<FISM_B, 256, 0, stream>>>(
        item_lst, past_item_lst, len_past_items,
        item_table, past_item_table, item_bias_table, out);
}